// Round 1
// baseline (126.612 us; speedup 1.0000x reference)
//
#include <hip/hip_runtime.h>
#include <hip/hip_bf16.h>
#include <math.h>

typedef short bf16x8 __attribute__((ext_vector_type(8)));
typedef float f32x4 __attribute__((ext_vector_type(4)));
typedef unsigned int u32x4 __attribute__((ext_vector_type(4)));
typedef unsigned int u32x2 __attribute__((ext_vector_type(2)));

#define SEQ 2048
#define MD 1024
#define DH 128

__device__ __forceinline__ unsigned short f2b(float f) {
  union { __hip_bfloat16 h; unsigned short u; } c;
  c.h = __float2bfloat16(f);
  return c.u;
}

// ---------------------------------------------------------------------------
// Projection GEMM: X[16384,1024] (f32) x W[1024,128] (f32) -> bf16
// proj 0 -> q_ws [16384][128]; proj 1 -> k_ws [16384][128];
// proj 2 -> vt_ws [8][128][2048]  (V transposed per batch, for attn PV stage)
// 128x128 tile, BK=64, 4 waves of 64x64, XOR-swizzled bf16 LDS.
// ---------------------------------------------------------------------------
__global__ __launch_bounds__(256) void proj_kernel(
    const float* __restrict__ xq, const float* __restrict__ xk, const float* __restrict__ xv,
    const float* __restrict__ wq, const float* __restrict__ wk, const float* __restrict__ wv,
    __hip_bfloat16* __restrict__ q_ws, __hip_bfloat16* __restrict__ k_ws,
    __hip_bfloat16* __restrict__ vt_ws)
{
  const int proj = blockIdx.y;
  const float* __restrict__ x = (proj == 0) ? xq : ((proj == 1) ? xk : xv);
  const float* __restrict__ w = (proj == 0) ? wq : ((proj == 1) ? wk : wv);
  const int m0 = blockIdx.x * 128;
  const int tid = threadIdx.x;
  const int lane = tid & 63;
  const int wid = tid >> 6;
  const int ll = lane & 15;
  const int lh = lane >> 4;
  const int wrow = (wid >> 1) * 64;
  const int wcol = (wid & 1) * 64;

  __shared__ __hip_bfloat16 As[128 * 64];   // [row][k], swizzled
  __shared__ __hip_bfloat16 Bs[128 * 64];   // [n][k] (W transposed), swizzled
  char* Asb = (char*)As;
  char* Bsb = (char*)Bs;

  const f32x4 zero4 = {0.f, 0.f, 0.f, 0.f};
  f32x4 acc[4][4];
#pragma unroll
  for (int mi = 0; mi < 4; ++mi)
#pragma unroll
    for (int ni = 0; ni < 4; ++ni) acc[mi][ni] = zero4;

  const int bn = tid & 127;         // B staging: output column
  const int bk0 = (tid >> 7) * 32;  // B staging: k half

  for (int kt = 0; kt < MD / 64; ++kt) {
    // ---- stage A: 128 rows x 64 k, f32 -> bf16, swizzled ----
#pragma unroll
    for (int i = 0; i < 8; ++i) {
      int idx = tid + i * 256;          // 2048 float4-chunks / 8B bf16 chunks
      int row = idx >> 4;
      int kc = (idx & 15) << 2;         // float index within k-tile
      const f32x4 a = *reinterpret_cast<const f32x4*>(
          &x[(size_t)(m0 + row) * MD + kt * 64 + kc]);
      u32x2 pk;
      pk[0] = (unsigned)f2b(a[0]) | ((unsigned)f2b(a[1]) << 16);
      pk[1] = (unsigned)f2b(a[2]) | ((unsigned)f2b(a[3]) << 16);
      int byte = row * 128 + ((kc * 2) ^ ((row & 7) << 4));
      *reinterpret_cast<u32x2*>(Asb + byte) = pk;
    }
    // ---- stage B transposed: Bs[n][k], f32 -> bf16, swizzled ----
#pragma unroll
    for (int jj = 0; jj < 4; ++jj) {
      int kbase = kt * 64 + bk0 + jj * 8;
      u32x4 pk;
#pragma unroll
      for (int u = 0; u < 4; ++u) {
        float f0 = w[(size_t)(kbase + 2 * u) * DH + bn];
        float f1 = w[(size_t)(kbase + 2 * u + 1) * DH + bn];
        pk[u] = (unsigned)f2b(f0) | ((unsigned)f2b(f1) << 16);
      }
      int byte = bn * 128 + (((bk0 + jj * 8) * 2) ^ ((bn & 7) << 4));
      *reinterpret_cast<u32x4*>(Bsb + byte) = pk;
    }
    __syncthreads();

    // ---- MFMA: 2 k-slices of 32 ----
#pragma unroll
    for (int kk = 0; kk < 2; ++kk) {
      bf16x8 af[4], bfv[4];
#pragma unroll
      for (int mi = 0; mi < 4; ++mi) {
        int row = wrow + mi * 16 + ll;
        af[mi] = *reinterpret_cast<bf16x8*>(
            Asb + row * 128 + ((kk * 64 + lh * 16) ^ ((row & 7) << 4)));
      }
#pragma unroll
      for (int ni = 0; ni < 4; ++ni) {
        int n = wcol + ni * 16 + ll;
        bfv[ni] = *reinterpret_cast<bf16x8*>(
            Bsb + n * 128 + ((kk * 64 + lh * 16) ^ ((n & 7) << 4)));
      }
#pragma unroll
      for (int mi = 0; mi < 4; ++mi)
#pragma unroll
        for (int ni = 0; ni < 4; ++ni)
          acc[mi][ni] = __builtin_amdgcn_mfma_f32_16x16x32_bf16(
              af[mi], bfv[ni], acc[mi][ni], 0, 0, 0);
    }
    __syncthreads();
  }

  // ---- epilogue ----
  if (proj < 2) {
    __hip_bfloat16* outp = (proj == 0) ? q_ws : k_ws;
#pragma unroll
    for (int mi = 0; mi < 4; ++mi)
#pragma unroll
      for (int ni = 0; ni < 4; ++ni) {
        int col = wcol + ni * 16 + ll;
#pragma unroll
        for (int r = 0; r < 4; ++r) {
          int row = m0 + wrow + mi * 16 + lh * 4 + r;
          union { __hip_bfloat16 h; unsigned short u; } c;
          c.u = f2b(acc[mi][ni][r]);
          outp[(size_t)row * DH + col] = c.h;
        }
      }
  } else {
    // V transposed: vt[b][d][s]; rows (l>>4)*4+r are consecutive s -> 8B store
    int b = m0 >> 11;
    int sb = m0 & 2047;
#pragma unroll
    for (int mi = 0; mi < 4; ++mi)
#pragma unroll
      for (int ni = 0; ni < 4; ++ni) {
        int s = sb + wrow + mi * 16 + lh * 4;
        int d = wcol + ni * 16 + ll;
        u32x2 pk;
        pk[0] = (unsigned)f2b(acc[mi][ni][0]) | ((unsigned)f2b(acc[mi][ni][1]) << 16);
        pk[1] = (unsigned)f2b(acc[mi][ni][2]) | ((unsigned)f2b(acc[mi][ni][3]) << 16);
        *reinterpret_cast<u32x2*>(&vt_ws[((size_t)b * DH + d) * SEQ + s]) = pk;
      }
  }
}

// ---------------------------------------------------------------------------
// Causal flash attention: q[16384][128], k[16384][128], vt[8][128][2048] bf16
// -> out f32 [8][2048][128].  QBLK=64 (4 waves x 16 rows), KVBLK=64.
// ---------------------------------------------------------------------------
__global__ __launch_bounds__(256) void attn_kernel(
    const __hip_bfloat16* __restrict__ q_ws, const __hip_bfloat16* __restrict__ k_ws,
    const __hip_bfloat16* __restrict__ vt_ws, float* __restrict__ out)
{
  const int qt = blockIdx.x;   // q tile (64 rows)
  const int b  = blockIdx.y;   // batch
  const int tid = threadIdx.x;
  const int lane = tid & 63;
  const int wid = tid >> 6;
  const int ll = lane & 15;
  const int lh = lane >> 4;

  __shared__ __hip_bfloat16 Ks[64 * 128];  // [kv][d], swizzled
  __shared__ __hip_bfloat16 Vs[128 * 64];  // [d][kv], swizzled
  __shared__ float Ps[64 * 64];            // [kv][q] f32, swizzled; wave-private cols
  char* Ksb = (char*)Ks;
  char* Vsb = (char*)Vs;
  char* Psb = (char*)Ps;

  // Q fragments: wave owns q rows qt*64 + wid*16 .. +15
  bf16x8 qf[4];
  {
    const size_t qbase = ((size_t)b * SEQ + qt * 64 + wid * 16 + ll) * DH;
#pragma unroll
    for (int kk = 0; kk < 4; ++kk)
      qf[kk] = *reinterpret_cast<const bf16x8*>(&q_ws[qbase + kk * 32 + lh * 8]);
  }

  const f32x4 zero4 = {0.f, 0.f, 0.f, 0.f};
  float m_r[4], l_r[4];
  f32x4 oacc[8];
#pragma unroll
  for (int r = 0; r < 4; ++r) { m_r[r] = -INFINITY; l_r[r] = 0.f; }
#pragma unroll
  for (int nd = 0; nd < 8; ++nd) oacc[nd] = zero4;

  // fold 1/sqrt(128) and log2(e) so exp is exp2
  const float sl2e = 0.0883883476483184f * 1.4426950408889634f;

  const int niter = qt + 1;
  for (int it = 0; it < niter; ++it) {
    const int kv0 = it * 64;
    // ---- stage K tile [64][128] ----
#pragma unroll
    for (int i = 0; i < 4; ++i) {
      int id = tid + i * 256;
      int row = id >> 4;
      int cb = (id & 15) << 4;  // byte col within 256B row
      u32x4 v = *reinterpret_cast<const u32x4*>(
          &k_ws[((size_t)b * SEQ + kv0 + row) * DH + (cb >> 1)]);
      *reinterpret_cast<u32x4*>(Ksb + row * 256 + (cb ^ ((row & 7) << 4))) = v;
    }
    // ---- stage V^T tile [128][64] (already transposed in ws) ----
#pragma unroll
    for (int i = 0; i < 4; ++i) {
      int id = tid + i * 256;
      int d = id >> 3;
      int cb = (id & 7) << 4;   // byte col within 128B row
      u32x4 v = *reinterpret_cast<const u32x4*>(
          &vt_ws[((size_t)b * DH + d) * SEQ + kv0 + (cb >> 1)]);
      *reinterpret_cast<u32x4*>(Vsb + d * 128 + (cb ^ ((d & 7) << 4))) = v;
    }
    __syncthreads();

    // ---- S = Q K^T (16 x 64 per wave) ----
    f32x4 sacc[4];
#pragma unroll
    for (int nf = 0; nf < 4; ++nf) sacc[nf] = zero4;
#pragma unroll
    for (int nf = 0; nf < 4; ++nf) {
      int row = nf * 16 + ll;
#pragma unroll
      for (int kk = 0; kk < 4; ++kk) {
        bf16x8 kf = *reinterpret_cast<bf16x8*>(
            Ksb + row * 256 + ((kk * 64 + lh * 16) ^ ((row & 7) << 4)));
        sacc[nf] = __builtin_amdgcn_mfma_f32_16x16x32_bf16(qf[kk], kf, sacc[nf], 0, 0, 0);
      }
    }

    // ---- scale + causal mask (lane holds S[lh*4+r][nf*16+ll]) ----
    float sv[4][4];
    const int qr0 = qt * 64 + wid * 16 + lh * 4;
#pragma unroll
    for (int nf = 0; nf < 4; ++nf) {
      int kc = kv0 + nf * 16 + ll;
#pragma unroll
      for (int r = 0; r < 4; ++r) {
        float s = sacc[nf][r] * sl2e;
        sv[nf][r] = (kc <= qr0 + r) ? s : -INFINITY;
      }
    }

    // ---- online softmax per row (reduce across the 16 ll-lanes) ----
    float p[4][4];  // [nf][r]
    float alpha[4];
#pragma unroll
    for (int r = 0; r < 4; ++r) {
      float mx = fmaxf(fmaxf(sv[0][r], sv[1][r]), fmaxf(sv[2][r], sv[3][r]));
#pragma unroll
      for (int off = 1; off < 16; off <<= 1)
        mx = fmaxf(mx, __shfl_xor(mx, off));
      float mnew = fmaxf(m_r[r], mx);
      float sum = 0.f;
#pragma unroll
      for (int nf = 0; nf < 4; ++nf) {
        float pv = exp2f(sv[nf][r] - mnew);
        p[nf][r] = pv;
        sum += pv;
      }
#pragma unroll
      for (int off = 1; off < 16; off <<= 1)
        sum += __shfl_xor(sum, off);
      alpha[r] = exp2f(m_r[r] - mnew);
      l_r[r] = l_r[r] * alpha[r] + sum;
      m_r[r] = mnew;
    }
    // rescale O
#pragma unroll
    for (int nd = 0; nd < 8; ++nd)
#pragma unroll
      for (int r = 0; r < 4; ++r) oacc[nd][r] *= alpha[r];

    // ---- P^T -> LDS (wave-private columns; no barrier needed) ----
#pragma unroll
    for (int nf = 0; nf < 4; ++nf) {
      int kv = nf * 16 + ll;
      f32x4 pv4 = {p[nf][0], p[nf][1], p[nf][2], p[nf][3]};
      *reinterpret_cast<f32x4*>(
          Psb + kv * 256 + ((wid * 64 + lh * 16) ^ ((kv & 7) << 4))) = pv4;
    }

    // ---- O += P V ----
#pragma unroll
    for (int kf = 0; kf < 2; ++kf) {
      float pf[8];
#pragma unroll
      for (int j = 0; j < 8; ++j) {
        int kv = kf * 32 + lh * 8 + j;
        pf[j] = *reinterpret_cast<float*>(
            Psb + kv * 256 + ((wid * 64 + ll * 4) ^ ((kv & 7) << 4)));
      }
      bf16x8 pa;
#pragma unroll
      for (int j = 0; j < 8; ++j) pa[j] = (short)f2b(pf[j]);
#pragma unroll
      for (int nd = 0; nd < 8; ++nd) {
        int d = nd * 16 + ll;
        bf16x8 vf = *reinterpret_cast<bf16x8*>(
            Vsb + d * 128 + ((kf * 64 + lh * 16) ^ ((d & 7) << 4)));
        oacc[nd] = __builtin_amdgcn_mfma_f32_16x16x32_bf16(pa, vf, oacc[nd], 0, 0, 0);
      }
    }
    __syncthreads();
  }

  // ---- epilogue: normalize and store f32 ----
  float inv[4];
#pragma unroll
  for (int r = 0; r < 4; ++r) inv[r] = 1.0f / l_r[r];
#pragma unroll
  for (int nd = 0; nd < 8; ++nd) {
    int d = nd * 16 + ll;
#pragma unroll
    for (int r = 0; r < 4; ++r) {
      size_t row = (size_t)b * SEQ + qt * 64 + wid * 16 + lh * 4 + r;
      out[row * DH + d] = oacc[nd][r] * inv[r];
    }
  }
}

extern "C" void kernel_launch(void* const* d_in, const int* in_sizes, int n_in,
                              void* d_out, int out_size, void* d_ws, size_t ws_size,
                              hipStream_t stream) {
  const float* xq = (const float*)d_in[0];
  const float* xk = (const float*)d_in[1];
  const float* xv = (const float*)d_in[2];
  const float* wq = (const float*)d_in[3];
  const float* wk = (const float*)d_in[4];
  const float* wv = (const float*)d_in[5];

  __hip_bfloat16* q_ws = (__hip_bfloat16*)d_ws;
  __hip_bfloat16* k_ws = q_ws + (size_t)16384 * 128;
  __hip_bfloat16* vt_ws = k_ws + (size_t)16384 * 128;
  float* out = (float*)d_out;

  proj_kernel<<<dim3(128, 3), 256, 0, stream>>>(xq, xk, xv, wq, wk, wv,
                                                q_ws, k_ws, vt_ws);
  attn_kernel<<<dim3(32, 8), 256, 0, stream>>>(q_ws, k_ws, vt_ws, out);
}